// Round 8
// baseline (292.072 us; speedup 1.0000x reference)
//
#include <hip/hip_runtime.h>
#include <stdint.h>

typedef unsigned short u16;
typedef __attribute__((ext_vector_type(4))) short short4v;
typedef __attribute__((ext_vector_type(8))) short bf16x8;
typedef __attribute__((ext_vector_type(4))) float f32x4;
typedef __attribute__((ext_vector_type(16))) float f32x16;
typedef __attribute__((ext_vector_type(4))) uint32_t u32x4;
typedef __attribute__((ext_vector_type(2))) int int2v;

#define T_LEN 2048
#define D_DIM 1024
#define H_DIM 128
// sqrt(128) * log2(e)
#define SCALE_LOG2 16.32223116f

#define EXP2F(x) __builtin_amdgcn_exp2f(x)

__device__ __forceinline__ u16 f2bf(float f) {
  uint32_t u = __float_as_uint(f);
  u += 0x7FFFu + ((u >> 16) & 1u);
  return (u16)(u >> 16);
}
__device__ __forceinline__ float bf2f(u16 h) { return __uint_as_float(((uint32_t)h) << 16); }

__device__ __forceinline__ void gload16(const void* g, void* l) {
  __builtin_amdgcn_global_load_lds(
      (const __attribute__((address_space(1))) uint32_t*)(uintptr_t)g,
      (__attribute__((address_space(3))) uint32_t*)(uint32_t)(uintptr_t)l,
      16, 0, 0);
}

#define VMLG0() asm volatile("s_waitcnt vmcnt(0) lgkmcnt(0)" ::: "memory")
#define VMC8() asm volatile("s_waitcnt vmcnt(8)" ::: "memory")
#define CFENCE() asm volatile("" ::: "memory")
#define BAR() __builtin_amdgcn_s_barrier()
#define PRIO(n) __builtin_amdgcn_s_setprio(n)

#define MFMA(a, b, c) __builtin_amdgcn_mfma_f32_16x16x32_bf16((a), (b), (c), 0, 0, 0)
#define MFMA32(a, b, c) __builtin_amdgcn_mfma_f32_32x32x16_bf16((a), (b), (c), 0, 0, 0)

__device__ __forceinline__ uint32_t cvtpk(float lo, float hi) {
  uint32_t r;
  asm("v_cvt_pk_bf16_f32 %0, %1, %2" : "=v"(r) : "v"(lo), "v"(hi));
  return r;
}
__device__ __forceinline__ void plswap(uint32_t& a, uint32_t& b, int hi) {
#if __has_builtin(__builtin_amdgcn_permlane32_swap)
  int2v r = __builtin_amdgcn_permlane32_swap((int)a, (int)b, false, false);
  a = (uint32_t)r.x;
  b = (uint32_t)r.y;
#else
  uint32_t as = (uint32_t)__shfl_xor((int)a, 32);
  uint32_t bs = (uint32_t)__shfl_xor((int)b, 32);
  uint32_t na = hi ? bs : a;
  uint32_t nb = hi ? b : as;
  a = na;
  b = nb;
#endif
}

// ---------------------------------------------------------------------------
// Kernel 0: split W matrices into bf16 hi/lo planes, transposed to wT[h][d].
// ---------------------------------------------------------------------------
__global__ __launch_bounds__(256) void prep_w(
    const float* __restrict__ Wk, const float* __restrict__ Wq, const float* __restrict__ Wv,
    u16* __restrict__ wqh, u16* __restrict__ wql,
    u16* __restrict__ wkh, u16* __restrict__ wkl,
    u16* __restrict__ wvh) {
  __shared__ u16 th[3][128][16];
  __shared__ u16 tl[2][128][16];
  const int i = threadIdx.x;
  const int d0 = blockIdx.x * 16;
  const int dl = i >> 4;
  const int hb = (i & 15) * 8;
  const int d = d0 + dl;
#pragma unroll
  for (int e = 0; e < 8; ++e) {
    int h = hb + e;
    float q = Wq[d * H_DIM + h] * SCALE_LOG2;
    float k = Wk[d * H_DIM + h];
    float v = Wv[d * H_DIM + h];
    u16 qh = f2bf(q); th[0][h][dl] = qh; tl[0][h][dl] = f2bf(q - bf2f(qh));
    u16 kh = f2bf(k); th[1][h][dl] = kh; tl[1][h][dl] = f2bf(k - bf2f(kh));
    th[2][h][dl] = f2bf(v);
  }
  __syncthreads();
  const int h = i >> 1, c = i & 1;
  u16* planes[5] = {wqh, wql, wkh, wkl, wvh};
  const u16* srcs[5] = {&th[0][0][0], &tl[0][0][0], &th[1][0][0], &tl[1][0][0], &th[2][0][0]};
#pragma unroll
  for (int p = 0; p < 5; ++p) {
    bf16x8 v8 = *(const bf16x8*)(srcs[p] + h * 16 + c * 8);
    *(bf16x8*)(planes[p] + h * 1024 + d0 + c * 8) = v8;
  }
}

// ---------------------------------------------------------------------------
// Kernel 1: QKV projection. 512 blocks x 256 threads (32 rows/block, 4 waves),
// SINGLE 46 KB LDS buffer (A 6K + W 40K) -> 2-3 blocks/CU. Co-resident block
// fills the stage-drain stall. 2 barriers/iter. MFMA product-major ordering.
// ---------------------------------------------------------------------------
__global__ __launch_bounds__(256) void qkv_proj(
    const float* __restrict__ att, const float* __restrict__ x,
    const u16* __restrict__ wqh, const u16* __restrict__ wql,
    const u16* __restrict__ wkh, const u16* __restrict__ wkl,
    const u16* __restrict__ wvh,
    const float* __restrict__ bq, const float* __restrict__ bk, const float* __restrict__ bv,
    u16* __restrict__ qhp, u16* __restrict__ qlp,
    u16* __restrict__ khp, u16* __restrict__ klp,
    u16* __restrict__ vtp) {
  __shared__ __attribute__((aligned(128))) char lds[46 * 1024];
  char* const wt = lds + 6144;  // 5 planes x 8 KB, each [128 h][64 B]

  const int tid = threadIdx.x;
  const int wid = tid >> 6;
  const int ln = tid & 63;
  const int g = ln >> 4;
  const int cl = ln & 15;
  const int t0g = blockIdx.x * 32;

  const f32x4 fz = {0.f, 0.f, 0.f, 0.f};
  f32x4 accq[2][2], acck[2][2], accv[2][2];
#pragma unroll
  for (int a = 0; a < 2; ++a)
#pragma unroll
    for (int s = 0; s < 2; ++s) { accq[a][s] = fz; acck[a][s] = fz; accv[a][s] = fz; }

  // A staging: 32 rows x 32 k fp32; thread owns one f32x4 of att AND x
  const int arow = tid >> 3;   // 0..31
  const int ac = tid & 7;      // 4-float chunk within k-slice
  const float* srcA = att + (size_t)(t0g + arow) * D_DIM + ac * 4;
  const float* srcX = x + (size_t)(t0g + arow) * D_DIM + ac * 4;
  const int awb = arow * 64 + (((ac >> 1) ^ ((arow >> 1) & 3)) * 16) + (ac & 1) * 8;

  auto STAGE_W = [&](int ks) {
#pragma unroll
    for (int j = 0; j < 10; ++j) {
      int seg = wid * 10 + j;  // 0..39
      int p = seg >> 3;
      int s = seg & 7;
      int db = s * 1024 + ln * 16;
      int row = db >> 6;
      int c = (db >> 4) & 3;
      int cs = c ^ ((row >> 1) & 3);
      const u16* wp = (p == 0) ? wqh : (p == 1) ? wql : (p == 2) ? wkh : (p == 3) ? wkl : wvh;
      gload16(wp + row * 1024 + ks * 32 + cs * 8, wt + p * 8192 + s * 1024);
    }
  };
  auto CWRITE_A = [&](f32x4 fa, f32x4 fx) {
    short4v vh, vl, vx;
#pragma unroll
    for (int e = 0; e < 4; ++e) {
      u16 h0 = f2bf(fa[e]); vh[e] = (short)h0; vl[e] = (short)f2bf(fa[e] - bf2f(h0));
      vx[e] = (short)f2bf(fx[e]);
    }
    *(short4v*)(lds + awb) = vh;
    *(short4v*)(lds + 2048 + awb) = vl;
    *(short4v*)(lds + 4096 + awb) = vx;
  };

  f32x4 pA = *(const f32x4*)(srcA);
  f32x4 pX = *(const f32x4*)(srcX);

  for (int ks = 0; ks < 32; ++ks) {
    if (ks) BAR();           // previous compute done; buffer writable
    CWRITE_A(pA, pX);        // pA loaded last iter (had compute time to land)
    STAGE_W(ks);
    VMLG0();                 // drain W stage (other block's compute covers)
    BAR();
    if (ks < 31) {
      pA = *(const f32x4*)(srcA + (ks + 1) * 32);
      pX = *(const f32x4*)(srcX + (ks + 1) * 32);
    }
    // --- compute ---
    bf16x8 ah[2], al[2], xh[2];
#pragma unroll
    for (int s = 0; s < 2; ++s) {
      int row = s * 16 + cl;
      int byte = row * 64 + ((g ^ ((row >> 1) & 3)) * 16);
      ah[s] = *(const bf16x8*)(lds + byte);
      al[s] = *(const bf16x8*)(lds + 2048 + byte);
      xh[s] = *(const bf16x8*)(lds + 4096 + byte);
    }
    bf16x8 bqh_[2], bql_[2], bkh_[2], bkl_[2], bvh_[2];
#pragma unroll
    for (int lnt = 0; lnt < 2; ++lnt) {
      int hrow = (2 * wid + lnt) * 16 + cl;
      int wb = hrow * 64 + ((g ^ ((hrow >> 1) & 3)) * 16);
      bqh_[lnt] = *(const bf16x8*)(wt + 0 * 8192 + wb);
      bql_[lnt] = *(const bf16x8*)(wt + 1 * 8192 + wb);
      bkh_[lnt] = *(const bf16x8*)(wt + 2 * 8192 + wb);
      bkl_[lnt] = *(const bf16x8*)(wt + 3 * 8192 + wb);
      bvh_[lnt] = *(const bf16x8*)(wt + 4 * 8192 + wb);
    }
    PRIO(1);
    // product-major: dependent accumulator reuse spaced by 4 MFMAs
#pragma unroll
    for (int lnt = 0; lnt < 2; ++lnt)
#pragma unroll
      for (int s = 0; s < 2; ++s) accq[lnt][s] = MFMA(ah[s], bqh_[lnt], accq[lnt][s]);
#pragma unroll
    for (int lnt = 0; lnt < 2; ++lnt)
#pragma unroll
      for (int s = 0; s < 2; ++s) accq[lnt][s] = MFMA(al[s], bqh_[lnt], accq[lnt][s]);
#pragma unroll
    for (int lnt = 0; lnt < 2; ++lnt)
#pragma unroll
      for (int s = 0; s < 2; ++s) accq[lnt][s] = MFMA(ah[s], bql_[lnt], accq[lnt][s]);
#pragma unroll
    for (int lnt = 0; lnt < 2; ++lnt)
#pragma unroll
      for (int s = 0; s < 2; ++s) acck[lnt][s] = MFMA(ah[s], bkh_[lnt], acck[lnt][s]);
#pragma unroll
    for (int lnt = 0; lnt < 2; ++lnt)
#pragma unroll
      for (int s = 0; s < 2; ++s) acck[lnt][s] = MFMA(al[s], bkh_[lnt], acck[lnt][s]);
#pragma unroll
    for (int lnt = 0; lnt < 2; ++lnt)
#pragma unroll
      for (int s = 0; s < 2; ++s) acck[lnt][s] = MFMA(ah[s], bkl_[lnt], acck[lnt][s]);
#pragma unroll
    for (int lnt = 0; lnt < 2; ++lnt)
#pragma unroll
      for (int s = 0; s < 2; ++s) accv[lnt][s] = MFMA(xh[s], bvh_[lnt], accv[lnt][s]);
    PRIO(0);
  }

  __syncthreads();
  // --- epilogue: bias, split q/k, write planes; v -> LDS transpose buffer ---
  char* vbuf = lds;  // [128 h][64 B] = 8 KB
#pragma unroll
  for (int lnt = 0; lnt < 2; ++lnt) {
    int h = (2 * wid + lnt) * 16 + cl;
    float bqv = bq[h] * SCALE_LOG2, bkv = bk[h], bvv = bv[h];
#pragma unroll
    for (int s = 0; s < 2; ++s) {
#pragma unroll
      for (int r = 0; r < 4; ++r) {
        int t = s * 16 + g * 4 + r;
        size_t idx = (size_t)(t0g + t) * H_DIM + h;
        float qv = accq[lnt][s][r] + bqv;
        u16 qh_ = f2bf(qv);
        qhp[idx] = qh_;
        qlp[idx] = f2bf(qv - bf2f(qh_));
        float kv = acck[lnt][s][r] + bkv;
        u16 kh_ = f2bf(kv);
        khp[idx] = kh_;
        klp[idx] = f2bf(kv - bf2f(kh_));
        float vv = accv[lnt][s][r] + bvv;
        int c3 = t >> 3;
        int byte = h * 64 + ((c3 ^ (h & 3)) * 16) + (t & 7) * 2;
        *(u16*)(vbuf + byte) = f2bf(vv);
      }
    }
  }
  __syncthreads();
  // --- vT coalesced writeout (32 t per block) ---
  {
    int h = tid >> 1, half = tid & 1;
    int b2 = t0g >> 11;
    int tb = t0g & 2047;
    u16* dst = vtp + ((size_t)(b2 * H_DIM + h)) * T_LEN + tb + half * 16;
#pragma unroll
    for (int c2 = 0; c2 < 2; ++c2) {
      int c3 = half * 2 + c2;
      bf16x8 v8 = *(const bf16x8*)(vbuf + h * 64 + ((c3 ^ (h & 3)) * 16));
      *(bf16x8*)(dst + c2 * 8) = v8;
    }
  }
}

// ---------------------------------------------------------------------------
// Kernel 2: flash attention. 512 blocks x 256 threads (32 q-rows, 4 waves =
// 4 kv-quarters). Each wave OWNS its 16 KB K-buffer -> NO barriers in the
// main loop; self-paced counted-vmcnt pipeline:
//   STAGE(t) || LOADV(t) -> SMPV(t-1) -> vmcnt(8) -> QK^T(t)
// LDS 64 KB -> 2 blocks/CU. Swapped QK^T, in-register softmax, defer-max.
// ---------------------------------------------------------------------------
#define KVB 32
#define NT 16  // tiles per quarter (512 kv / 32)

__global__ __launch_bounds__(256, 2) void attn(
    const u16* __restrict__ qhp, const u16* __restrict__ qlp,
    const u16* __restrict__ khp, const u16* __restrict__ klp,
    const u16* __restrict__ vtp,
    float* __restrict__ out) {
  __shared__ __attribute__((aligned(128))) char lds[64 * 1024];

  const int tid = threadIdx.x;
  const int kvq = tid >> 6;      // wave index = kv quarter
  const int l = tid & 63;
  const int q5 = l & 31;
  const int hi = l >> 5;
  const int bid = blockIdx.x;
  const int b_ = bid & 7;        // batch -> XCD
  const int t0 = (bid >> 3) * 32;
  const int qrow = t0 + q5;
  const int kv0q = kvq * 512;

  // ---- Q fragments (hi/lo) in registers ----
  bf16x8 qh[8], ql[8];
  {
    const u16* qb = qhp + (size_t)(b_ * T_LEN + qrow) * H_DIM + hi * 8;
    const u16* qlb = qlp + (size_t)(b_ * T_LEN + qrow) * H_DIM + hi * 8;
#pragma unroll
    for (int kc = 0; kc < 8; ++kc) {
      qh[kc] = *(const bf16x8*)(qb + kc * 16);
      ql[kc] = *(const bf16x8*)(qlb + kc * 16);
    }
  }

  // ---- staging decode: 16 gload16 per wave (16 KB tile: K hi 8K + lo 8K) ----
  uint32_t sgoff[16];
#pragma unroll
  for (int i = 0; i < 16; ++i) {
    int n = i * 64 + l;          // 0..1023
    int plane = n >> 9;
    int m = n & 511;
    int row = m >> 4;            // 0..31
    int slot = m & 15;
    int dg = slot ^ (row & 15);  // XOR-swizzle folded into global source
    sgoff[i] = (uint32_t)(plane * 2097152 + (b_ * T_LEN + row) * H_DIM + dg * 8);
  }
  char* const kbase = lds + kvq * 16384;

  auto STAGE = [&](int kvoff) {
#pragma unroll
    for (int i = 0; i < 16; ++i)
      gload16(khp + sgoff[i] + (uint32_t)(kvoff * H_DIM), kbase + i * 1024);
  };
  auto LOADV = [&](int tv, bf16x8* v) {
#pragma unroll
    for (int ks = 0; ks < 2; ++ks)
#pragma unroll
      for (int nt = 0; nt < 4; ++nt)
        v[ks * 4 + nt] = *(const bf16x8*)(
            vtp + (size_t)(b_ * H_DIM + nt * 32 + q5) * T_LEN +
            kv0q + tv * KVB + ks * 16 + hi * 8);
  };

  f32x16 o[4] = {};
  float m_ = -1e30f;
  float l_ = 0.f;
  f32x16 s_prev;
  bf16x8 vfr[8], vnx[8];

  auto QKT = [&]() {
    const char* kb = kbase + q5 * 256;
    f32x16 s0 = {}, s1 = {}, s2 = {};
    PRIO(1);
#pragma unroll
    for (int kc = 0; kc < 8; ++kc) {
      int so = (((kc * 2 + hi) ^ (q5 & 15)) * 16);
      bf16x8 khf = *(const bf16x8*)(kb + so);
      bf16x8 klf = *(const bf16x8*)(kb + 8192 + so);
      s0 = MFMA32(khf, qh[kc], s0);
      s1 = MFMA32(klf, qh[kc], s1);
      s2 = MFMA32(khf, ql[kc], s2);
    }
    PRIO(0);
    s_prev = (s0 + s1) + s2;
  };

  auto SMPV = [&]() {
    float t01 = fmaxf(s_prev[0], s_prev[1]), t23 = fmaxf(s_prev[2], s_prev[3]);
    float t45 = fmaxf(s_prev[4], s_prev[5]), t67 = fmaxf(s_prev[6], s_prev[7]);
    float t89 = fmaxf(s_prev[8], s_prev[9]), tab = fmaxf(s_prev[10], s_prev[11]);
    float tcd = fmaxf(s_prev[12], s_prev[13]), tef = fmaxf(s_prev[14], s_prev[15]);
    float q0 = fmaxf(t01, t23), q1 = fmaxf(t45, t67);
    float q2 = fmaxf(t89, tab), q3 = fmaxf(tcd, tef);
    float pmax = fmaxf(fmaxf(q0, q1), fmaxf(q2, q3));
    pmax = fmaxf(pmax, __shfl_xor(pmax, 32));
    if (__any(pmax > m_ + 8.f)) {
      float mn = fmaxf(m_, pmax);
      float sf = EXP2F(m_ - mn);
      m_ = mn;
      l_ *= sf;
#pragma unroll
      for (int j = 0; j < 16; ++j) {
        int rj = (j & 3) + 8 * (j >> 2) + 4 * hi;
        float sfj = __shfl(sf, rj);
        o[0][j] *= sfj; o[1][j] *= sfj; o[2][j] *= sfj; o[3][j] *= sfj;
      }
    }
    float p[16];
#pragma unroll
    for (int j = 0; j < 16; ++j) p[j] = EXP2F(s_prev[j] - m_);
    float a0 = p[0] + p[1], a1 = p[2] + p[3], a2 = p[4] + p[5], a3 = p[6] + p[7];
    float a4 = p[8] + p[9], a5 = p[10] + p[11], a6 = p[12] + p[13], a7 = p[14] + p[15];
    float b0 = a0 + a1, b1 = a2 + a3, b2 = a4 + a5, b3 = a6 + a7;
    float ps = (b0 + b1) + (b2 + b3);
    ps += __shfl_xor(ps, 32);
    l_ += ps;

    uint32_t u0 = cvtpk(p[0], p[1]), v0 = cvtpk(p[4], p[5]);
    uint32_t u1 = cvtpk(p[2], p[3]), v1 = cvtpk(p[6], p[7]);
    uint32_t u2 = cvtpk(p[8], p[9]), v2 = cvtpk(p[12], p[13]);
    uint32_t u3 = cvtpk(p[10], p[11]), v3 = cvtpk(p[14], p[15]);
    plswap(u0, v0, hi);
    plswap(u1, v1, hi);
    plswap(u2, v2, hi);
    plswap(u3, v3, hi);
    u32x4 f0w = {u0, u1, v0, v1};
    u32x4 f1w = {u2, u3, v2, v3};
    bf16x8 pa0 = *(bf16x8*)&f0w;
    bf16x8 pa1 = *(bf16x8*)&f1w;
    PRIO(1);
#pragma unroll
    for (int nt = 0; nt < 4; ++nt) o[nt] = MFMA32(pa0, vfr[nt], o[nt]);
#pragma unroll
    for (int nt = 0; nt < 4; ++nt) o[nt] = MFMA32(pa1, vfr[4 + nt], o[nt]);
    PRIO(0);
  };

  // ---- prologue: tile 0 ----
  STAGE(kv0q);
  LOADV(0, vnx);
  VMC8();            // stage(0) landed; V(0) may fly
  QKT();
#pragma unroll
  for (int nt = 0; nt < 8; ++nt) vfr[nt] = vnx[nt];  // waits V(0)
  CFENCE();

  // ---- main loop: no barriers (each wave owns its K-buffer) ----
  for (int t = 1; t < NT; ++t) {
    STAGE(kv0q + t * KVB);   // overwrite own buffer (QKT(t-1) reads retired)
    LOADV(t, vnx);
    SMPV();                  // softmax+PV (t-1): covers stage latency
    VMC8();                  // stage(t) landed; V(t) still in flight
    QKT();                   // tile t
#pragma unroll
    for (int nt = 0; nt < 8; ++nt) vfr[nt] = vnx[nt];  // waits V(t)
    CFENCE();
  }
  SMPV();                    // tile NT-1

  // ---- 4-way split-KV merge ----
  float* mlb = (float*)(lds + 63 * 1024);
  __syncthreads();
  if (hi == 0) {
    mlb[kvq * 64 + q5 * 2] = m_;
    mlb[kvq * 64 + q5 * 2 + 1] = l_;
  }
  __syncthreads();
  float sc;
  {
    float ms0 = mlb[0 * 64 + q5 * 2], ls0 = mlb[0 * 64 + q5 * 2 + 1];
    float ms1 = mlb[1 * 64 + q5 * 2], ls1 = mlb[1 * 64 + q5 * 2 + 1];
    float ms2 = mlb[2 * 64 + q5 * 2], ls2 = mlb[2 * 64 + q5 * 2 + 1];
    float ms3 = mlb[3 * 64 + q5 * 2], ls3 = mlb[3 * 64 + q5 * 2 + 1];
    float mM = fmaxf(fmaxf(ms0, ms1), fmaxf(ms2, ms3));
    float L = ls0 * EXP2F(ms0 - mM) + ls1 * EXP2F(ms1 - mM) +
              ls2 * EXP2F(ms2 - mM) + ls3 * EXP2F(ms3 - mM);
    sc = EXP2F(m_ - mM) / L;
  }
#pragma unroll
  for (int j = 0; j < 16; ++j) {
    int rj = (j & 3) + 8 * (j >> 2) + 4 * hi;
    float scj = __shfl(sc, rj);
    o[0][j] *= scj; o[1][j] *= scj; o[2][j] *= scj; o[3][j] *= scj;
  }
  if (kvq != 0) {
    float* ob = (float*)(lds + (kvq - 1) * 16384);
#pragma unroll
    for (int nt = 0; nt < 4; ++nt)
#pragma unroll
      for (int j = 0; j < 16; ++j) ob[nt * 1024 + j * 64 + l] = o[nt][j];
  }
  __syncthreads();
  if (kvq == 0) {
    float* ob0 = (float*)(lds + 0 * 16384);
    float* ob1 = (float*)(lds + 1 * 16384);
    float* ob2 = (float*)(lds + 2 * 16384);
#pragma unroll
    for (int j = 0; j < 16; ++j) {
      int rj = (j & 3) + 8 * (j >> 2) + 4 * hi;
      size_t rbase = (size_t)(b_ * T_LEN + t0 + rj) * H_DIM + q5;
#pragma unroll
      for (int nt = 0; nt < 4; ++nt) {
        int oi = nt * 1024 + j * 64 + l;
        out[rbase + nt * 32] = o[nt][j] + ob0[oi] + ob1[oi] + ob2[oi];
      }
    }
  }
}

// ---------------------------------------------------------------------------
extern "C" void kernel_launch(void* const* d_in, const int* in_sizes, int n_in,
                              void* d_out, int out_size, void* d_ws, size_t ws_size,
                              hipStream_t stream) {
  const float* x   = (const float*)d_in[0];
  const float* att = (const float*)d_in[1];
  const float* Wk  = (const float*)d_in[2];
  const float* bk  = (const float*)d_in[3];
  const float* Wq  = (const float*)d_in[4];
  const float* bq  = (const float*)d_in[5];
  const float* Wv  = (const float*)d_in[6];
  const float* bv  = (const float*)d_in[7];
  float* out = (float*)d_out;
  char* ws = (char*)d_ws;

  u16* wqh = (u16*)(ws);
  u16* wql = (u16*)(ws + 256 * 1024);
  u16* wkh = (u16*)(ws + 512 * 1024);
  u16* wkl = (u16*)(ws + 768 * 1024);
  u16* wvh = (u16*)(ws + 1024 * 1024);
  u16* qhp = (u16*)(ws + (size_t)2 * 1024 * 1024);
  u16* qlp = (u16*)(ws + (size_t)6 * 1024 * 1024);
  u16* khp = (u16*)(ws + (size_t)10 * 1024 * 1024);
  u16* klp = (u16*)(ws + (size_t)14 * 1024 * 1024);  // khp + 2097152 elems
  u16* vtp = (u16*)(ws + (size_t)18 * 1024 * 1024);

  prep_w<<<64, 256, 0, stream>>>(Wk, Wq, Wv, wqh, wql, wkh, wkl, wvh);
  qkv_proj<<<512, 256, 0, stream>>>(att, x, wqh, wql, wkh, wkl, wvh,
                                    bq, bk, bv, qhp, qlp, khp, klp, vtp);
  attn<<<512, 256, 0, stream>>>(qhp, qlp, khp, klp, vtp, out);
}